// Round 2
// baseline (350.018 us; speedup 1.0000x reference)
//
#include <hip/hip_runtime.h>
#include <hip/hip_bf16.h>

typedef __hip_bfloat16 bf16;
typedef short bf16x8_t __attribute__((ext_vector_type(8)));  // 8 bf16 = 4 VGPRs
typedef float f32x4_t __attribute__((ext_vector_type(4)));

#define NTOK 8192
#define INF  1024
#define OUTF 1024
#define GS   8
#define KTOT (INF + INF * GS)  // 9216

// ---------------- prep A: A[n,k] = bf16[ silu(x) | exp(-|x - grid_g|) ] ----------------
__global__ __launch_bounds__(256) void prep_a(const float* __restrict__ x,
                                              const float* __restrict__ grid,
                                              bf16* __restrict__ A) {
  const int idx = blockIdx.x * 256 + threadIdx.x;  // n*INF + i
  const int i = idx & (INF - 1);
  const int n = idx >> 10;
  const float xv = x[idx];
  const float s = xv / (1.0f + __expf(-xv));       // SiLU
  const size_t rowb = (size_t)n * KTOT;
  A[rowb + i] = __float2bfloat16(s);
  union { bf16x8_t v; bf16 h[8]; } kn;
  #pragma unroll
  for (int g = 0; g < 8; ++g) {
    const float gv = grid[i * 8 + g];
    kn.h[g] = __float2bfloat16(__expf(-fabsf(xv - gv)));  // sigma = 1
  }
  *(bf16x8_t*)(A + rowb + INF + (size_t)i * 8) = kn.v;
}

// ---------------- prep B: B[o,k] = bf16[ base_w | spline_w * scaler ] ----------------
__global__ __launch_bounds__(256) void prep_b(const float* __restrict__ bw,
                                              const float* __restrict__ sw,
                                              const float* __restrict__ ss,
                                              bf16* __restrict__ B) {
  const int idx = blockIdx.x * 256 + threadIdx.x;  // o*INF + i
  const int i = idx & (INF - 1);
  const int o = idx >> 10;
  const size_t rowb = (size_t)o * KTOT;
  B[rowb + i] = __float2bfloat16(bw[idx]);
  const float sc = ss[idx];
  const float4 w0 = *(const float4*)(sw + (size_t)idx * 8);
  const float4 w1 = *(const float4*)(sw + (size_t)idx * 8 + 4);
  union { bf16x8_t v; bf16 h[8]; } r8;
  r8.h[0] = __float2bfloat16(w0.x * sc);
  r8.h[1] = __float2bfloat16(w0.y * sc);
  r8.h[2] = __float2bfloat16(w0.z * sc);
  r8.h[3] = __float2bfloat16(w0.w * sc);
  r8.h[4] = __float2bfloat16(w1.x * sc);
  r8.h[5] = __float2bfloat16(w1.y * sc);
  r8.h[6] = __float2bfloat16(w1.z * sc);
  r8.h[7] = __float2bfloat16(w1.w * sc);
  *(bf16x8_t*)(B + rowb + INF + (size_t)i * 8) = r8.v;
}

// ---------------- GEMM: C[M,N] = A[M,K] * B[N,K]^T  (m97 recipe, fp32 out) ----------------
// 128x128 block tile, BK=64, 4 waves in 2x2, each wave 64x64 = 4x4 MFMA tiles
// of 16x16x32 bf16. Staging via global_load_lds width 16 (wave-uniform dest).
#define BM 128
#define BN 128
#define BK 64

__global__ __launch_bounds__(256) void gemm_bt(const bf16* __restrict__ A,
                                               const bf16* __restrict__ B,
                                               float* __restrict__ C) {
  __shared__ bf16 sA[BM * BK];  // [row][k] row-major, no pad (global_load_lds)
  __shared__ bf16 sB[BN * BK];

  const int t = threadIdx.x;
  const int lane = t & 63;
  const int w = t >> 6;            // wave 0..3
  const int wm = (w >> 1) * 64;    // wave quadrant row
  const int wn = (w & 1) * 64;     // wave quadrant col
  const int bc = blockIdx.x;       // N tile (0..7)
  const int br = blockIdx.y;       // M tile (0..63)

  // staging: thread t handles row (t>>3), k-chunk (t&7)*8 elems; LDS byte off = t*16
  const int srow = t >> 3;         // 0..31 (x4 insts -> 128 rows)
  const int scol = (t & 7) * 8;    // element offset in k
  const bf16* gA = A + (size_t)(br * BM + srow) * KTOT + scol;
  const bf16* gB = B + (size_t)(bc * BN + srow) * KTOT + scol;
  char* sAb = (char*)sA + w * 1024;  // wave-uniform dest base (+ lane*16 implicit)
  char* sBb = (char*)sB + w * 1024;

  // fragment addressing: A[m=lane&15][k=(lane>>4)*8 + j]
  const int frow = lane & 15;
  const int fk = (lane >> 4) * 8;

  f32x4_t acc[4][4] = {};

  for (int k0 = 0; k0 < KTOT; k0 += BK) {
    #pragma unroll
    for (int inst = 0; inst < 4; ++inst) {
      __builtin_amdgcn_global_load_lds(
          (const __attribute__((address_space(1))) void*)(gA + (size_t)inst * 32 * KTOT + k0),
          (__attribute__((address_space(3))) void*)(sAb + inst * 4096), 16, 0, 0);
      __builtin_amdgcn_global_load_lds(
          (const __attribute__((address_space(1))) void*)(gB + (size_t)inst * 32 * KTOT + k0),
          (__attribute__((address_space(3))) void*)(sBb + inst * 4096), 16, 0, 0);
    }
    __syncthreads();  // compiler emits vmcnt(0) drain before s_barrier
    #pragma unroll
    for (int kk = 0; kk < BK; kk += 32) {
      bf16x8_t af[4], bf_[4];
      #pragma unroll
      for (int i = 0; i < 4; ++i) {
        af[i]  = *(const bf16x8_t*)(sA + (wm + i * 16 + frow) * BK + kk + fk);
        bf_[i] = *(const bf16x8_t*)(sB + (wn + i * 16 + frow) * BK + kk + fk);
      }
      #pragma unroll
      for (int i = 0; i < 4; ++i)
        #pragma unroll
        for (int j = 0; j < 4; ++j)
          acc[i][j] = __builtin_amdgcn_mfma_f32_16x16x32_bf16(af[i], bf_[j], acc[i][j], 0, 0, 0);
    }
    __syncthreads();  // all reads done before next stage overwrites
  }

  // epilogue: D mapping col = lane&15, row = (lane>>4)*4 + reg  [m89/m91]
  const int ccol = bc * BN + wn + frow;
  const int crow0 = br * BM + wm + (lane >> 4) * 4;
  #pragma unroll
  for (int i = 0; i < 4; ++i)
    #pragma unroll
    for (int r = 0; r < 4; ++r) {
      float* cp = C + (size_t)(crow0 + i * 16 + r) * OUTF + ccol;
      #pragma unroll
      for (int j = 0; j < 4; ++j)
        cp[j * 16] = acc[i][j][r];
    }
}

// ---------------- fallback (ws too small): naive, correctness-only ----------------
__global__ __launch_bounds__(256) void naive_kern(const float* __restrict__ x,
                                                  const float* __restrict__ bw,
                                                  const float* __restrict__ sw,
                                                  const float* __restrict__ ss,
                                                  const float* __restrict__ grid,
                                                  float* __restrict__ out) {
  const int idx = blockIdx.x * 256 + threadIdx.x;  // n*OUTF + o
  const int o = idx & (OUTF - 1);
  const int n = idx >> 10;
  float acc = 0.f;
  for (int i = 0; i < INF; ++i) {
    const float xv = x[n * INF + i];
    const float s = xv / (1.f + __expf(-xv));
    acc += s * bw[o * INF + i];
    const float sc = ss[o * INF + i];
    #pragma unroll
    for (int g = 0; g < 8; ++g) {
      const float gv = grid[i * 8 + g];
      acc += __expf(-fabsf(xv - gv)) * sw[(size_t)(o * INF + i) * 8 + g] * sc;
    }
  }
  out[idx] = acc;
}

extern "C" void kernel_launch(void* const* d_in, const int* in_sizes, int n_in,
                              void* d_out, int out_size, void* d_ws, size_t ws_size,
                              hipStream_t stream) {
  const float* x    = (const float*)d_in[0];
  const float* bw   = (const float*)d_in[1];
  const float* sw   = (const float*)d_in[2];
  const float* ss   = (const float*)d_in[3];
  const float* grid = (const float*)d_in[4];
  float* out = (float*)d_out;

  const size_t needA = (size_t)NTOK * KTOT * sizeof(bf16);  // ~151 MB
  const size_t needB = (size_t)OUTF * KTOT * sizeof(bf16);  // ~19 MB

  if (ws_size >= needA + needB) {
    bf16* A = (bf16*)d_ws;
    bf16* B = (bf16*)((char*)d_ws + needA);
    prep_a<<<(NTOK * INF) / 256, 256, 0, stream>>>(x, grid, A);
    prep_b<<<(OUTF * INF) / 256, 256, 0, stream>>>(bw, sw, ss, B);
    dim3 g(OUTF / BN, NTOK / BM);  // (8, 64)
    gemm_bt<<<g, 256, 0, stream>>>(A, B, out);
  } else {
    naive_kern<<<(NTOK * OUTF) / 256, 256, 0, stream>>>(x, bw, sw, ss, grid, out);
  }
}

// Round 3
// 317.046 us; speedup vs baseline: 1.1040x; 1.1040x over previous
//
#include <hip/hip_runtime.h>
#include <hip/hip_bf16.h>

typedef __hip_bfloat16 bf16;
typedef short bf16x8_t __attribute__((ext_vector_type(8)));  // 8 bf16 = 4 VGPRs
typedef float f32x4_t __attribute__((ext_vector_type(4)));

#define NTOK 8192
#define INF  1024
#define OUTF 1024
#define GS   8
#define KTOT (INF + INF * GS)  // 9216

// ---------------- prep A: A[n,k] = bf16[ silu(x) | exp(-|x - grid_g|) ] ----------------
__global__ __launch_bounds__(256) void prep_a(const float* __restrict__ x,
                                              const float* __restrict__ grid,
                                              bf16* __restrict__ A) {
  const int idx = blockIdx.x * 256 + threadIdx.x;  // n*INF + i
  const int i = idx & (INF - 1);
  const int n = idx >> 10;
  const float xv = x[idx];
  const float s = xv / (1.0f + __expf(-xv));       // SiLU
  const size_t rowb = (size_t)n * KTOT;
  A[rowb + i] = __float2bfloat16(s);
  union { bf16x8_t v; bf16 h[8]; } kn;
  #pragma unroll
  for (int g = 0; g < 8; ++g) {
    const float gv = grid[i * 8 + g];
    kn.h[g] = __float2bfloat16(__expf(-fabsf(xv - gv)));  // sigma = 1
  }
  *(bf16x8_t*)(A + rowb + INF + (size_t)i * 8) = kn.v;
}

// ---------------- prep B: B[o,k] = bf16[ base_w | spline_w * scaler ] ----------------
__global__ __launch_bounds__(256) void prep_b(const float* __restrict__ bw,
                                              const float* __restrict__ sw,
                                              const float* __restrict__ ss,
                                              bf16* __restrict__ B) {
  const int idx = blockIdx.x * 256 + threadIdx.x;  // o*INF + i
  const int i = idx & (INF - 1);
  const int o = idx >> 10;
  const size_t rowb = (size_t)o * KTOT;
  B[rowb + i] = __float2bfloat16(bw[idx]);
  const float sc = ss[idx];
  const float4 w0 = *(const float4*)(sw + (size_t)idx * 8);
  const float4 w1 = *(const float4*)(sw + (size_t)idx * 8 + 4);
  union { bf16x8_t v; bf16 h[8]; } r8;
  r8.h[0] = __float2bfloat16(w0.x * sc);
  r8.h[1] = __float2bfloat16(w0.y * sc);
  r8.h[2] = __float2bfloat16(w0.z * sc);
  r8.h[3] = __float2bfloat16(w0.w * sc);
  r8.h[4] = __float2bfloat16(w1.x * sc);
  r8.h[5] = __float2bfloat16(w1.y * sc);
  r8.h[6] = __float2bfloat16(w1.z * sc);
  r8.h[7] = __float2bfloat16(w1.w * sc);
  *(bf16x8_t*)(B + rowb + INF + (size_t)i * 8) = r8.v;
}

// ---------------- GEMM: C[M,N] = A[M,K] * B[N,K]^T  (m97 recipe + XOR swizzle) ------
// 128x128 block tile, BK=64, 4 waves in 2x2, each wave 64x64 = 4x4 MFMA tiles of
// 16x16x32 bf16. Staging via global_load_lds width 16 (wave-uniform dest).
// LDS bank-conflict fix: row stride is 128 B = 32 banks, so un-swizzled fragment
// reads put all 16 lanes of a quarter-group on one 4-bank set (16-way conflict,
// measured 5.7e7 conflict-cycles = ~40% of runtime). We store 16-B k-chunk kc of
// row r at chunk slot (kc ^ (r&7)): the XOR folds into the staging SOURCE address
// (LDS dest of global_load_lds stays lane*16-contiguous) and into one XOR on the
// read side -> lanes spread over all 32 banks at 2-way aliasing (free per m136).
#define BM 128
#define BN 128
#define BK 64

__global__ __launch_bounds__(256) void gemm_bt(const bf16* __restrict__ A,
                                               const bf16* __restrict__ B,
                                               float* __restrict__ C) {
  __shared__ bf16 sA[BM * BK];
  __shared__ bf16 sB[BN * BK];

  const int t = threadIdx.x;
  const int lane = t & 63;
  const int w = t >> 6;            // wave 0..3
  const int wm = (w >> 1) * 64;    // wave quadrant row
  const int wn = (w & 1) * 64;     // wave quadrant col
  const int bc = blockIdx.x;       // N tile (0..7)
  const int br = blockIdx.y;       // M tile (0..63)

  // staging: thread t fills LDS slot (srow, chunk c) at byte offset t*16.
  // Swizzle: that slot must hold global k-chunk  kc = c ^ (srow&7).
  const int srow = t >> 3;                         // 0..31 (x4 insts -> 128 rows)
  const int scol = ((t & 7) ^ (srow & 7)) * 8;     // swizzled source k-offset (elems)
  const bf16* gA = A + (size_t)(br * BM + srow) * KTOT + scol;
  const bf16* gB = B + (size_t)(bc * BN + srow) * KTOT + scol;
  char* sAb = (char*)sA + w * 1024;  // wave-uniform dest base (+ lane*16 implicit)
  char* sBb = (char*)sB + w * 1024;

  // fragment addressing: A[m=lane&15][k=(lane>>4)*8 + j]
  const int frow = lane & 15;
  const int fk = (lane >> 4) * 8;
  const int fsw = frow & 7;        // row&7 for every fragment row (offsets = 0 mod 8)

  f32x4_t acc[4][4] = {};

  for (int k0 = 0; k0 < KTOT; k0 += BK) {
    #pragma unroll
    for (int inst = 0; inst < 4; ++inst) {   // +32 rows per inst: (row&7) unchanged
      __builtin_amdgcn_global_load_lds(
          (const __attribute__((address_space(1))) void*)(gA + (size_t)inst * 32 * KTOT + k0),
          (__attribute__((address_space(3))) void*)(sAb + inst * 4096), 16, 0, 0);
      __builtin_amdgcn_global_load_lds(
          (const __attribute__((address_space(1))) void*)(gB + (size_t)inst * 32 * KTOT + k0),
          (__attribute__((address_space(3))) void*)(sBb + inst * 4096), 16, 0, 0);
    }
    __syncthreads();
    #pragma unroll
    for (int kk = 0; kk < BK; kk += 32) {
      const int swk = ((((kk + fk) >> 3) ^ fsw) * 8);  // swizzled chunk -> elem offset
      bf16x8_t af[4], bf_[4];
      #pragma unroll
      for (int i = 0; i < 4; ++i) {
        af[i]  = *(const bf16x8_t*)(sA + (wm + i * 16 + frow) * BK + swk);
        bf_[i] = *(const bf16x8_t*)(sB + (wn + i * 16 + frow) * BK + swk);
      }
      #pragma unroll
      for (int i = 0; i < 4; ++i)
        #pragma unroll
        for (int j = 0; j < 4; ++j)
          acc[i][j] = __builtin_amdgcn_mfma_f32_16x16x32_bf16(af[i], bf_[j], acc[i][j], 0, 0, 0);
    }
    __syncthreads();
  }

  // epilogue: D mapping col = lane&15, row = (lane>>4)*4 + reg  [m89/m91]
  const int ccol = bc * BN + wn + frow;
  const int crow0 = br * BM + wm + (lane >> 4) * 4;
  #pragma unroll
  for (int i = 0; i < 4; ++i)
    #pragma unroll
    for (int r = 0; r < 4; ++r) {
      float* cp = C + (size_t)(crow0 + i * 16 + r) * OUTF + ccol;
      #pragma unroll
      for (int j = 0; j < 4; ++j)
        cp[j * 16] = acc[i][j][r];
    }
}

// ---------------- fallback (ws too small): naive, correctness-only ----------------
__global__ __launch_bounds__(256) void naive_kern(const float* __restrict__ x,
                                                  const float* __restrict__ bw,
                                                  const float* __restrict__ sw,
                                                  const float* __restrict__ ss,
                                                  const float* __restrict__ grid,
                                                  float* __restrict__ out) {
  const int idx = blockIdx.x * 256 + threadIdx.x;  // n*OUTF + o
  const int o = idx & (OUTF - 1);
  const int n = idx >> 10;
  float acc = 0.f;
  for (int i = 0; i < INF; ++i) {
    const float xv = x[n * INF + i];
    const float s = xv / (1.f + __expf(-xv));
    acc += s * bw[o * INF + i];
    const float sc = ss[o * INF + i];
    #pragma unroll
    for (int g = 0; g < 8; ++g) {
      const float gv = grid[i * 8 + g];
      acc += __expf(-fabsf(xv - gv)) * sw[(size_t)(o * INF + i) * 8 + g] * sc;
    }
  }
  out[idx] = acc;
}

extern "C" void kernel_launch(void* const* d_in, const int* in_sizes, int n_in,
                              void* d_out, int out_size, void* d_ws, size_t ws_size,
                              hipStream_t stream) {
  const float* x    = (const float*)d_in[0];
  const float* bw   = (const float*)d_in[1];
  const float* sw   = (const float*)d_in[2];
  const float* ss   = (const float*)d_in[3];
  const float* grid = (const float*)d_in[4];
  float* out = (float*)d_out;

  const size_t needA = (size_t)NTOK * KTOT * sizeof(bf16);  // ~151 MB
  const size_t needB = (size_t)OUTF * KTOT * sizeof(bf16);  // ~19 MB

  if (ws_size >= needA + needB) {
    bf16* A = (bf16*)d_ws;
    bf16* B = (bf16*)((char*)d_ws + needA);
    prep_a<<<(NTOK * INF) / 256, 256, 0, stream>>>(x, grid, A);
    prep_b<<<(OUTF * INF) / 256, 256, 0, stream>>>(bw, sw, ss, B);
    dim3 g(OUTF / BN, NTOK / BM);  // (8, 64)
    gemm_bt<<<g, 256, 0, stream>>>(A, B, out);
  } else {
    naive_kern<<<(NTOK * OUTF) / 256, 256, 0, stream>>>(x, bw, sw, ss, grid, out);
  }
}